// Round 6
// baseline (486.919 us; speedup 1.0000x reference)
//
#include <hip/hip_runtime.h>
#include <hip/hip_bf16.h>

#define BB 64
#define CC 32
#define HW2 256   // 16*16
#define VV 4096
#define NELEM (BB*CC*HW2)   // 524288
#define PADW 18
#define PADA 324  // 18*18

// ---------------- workspace layout (float offsets) ----------------
#define OFF_F     0
#define OFF_FHAT  (OFF_F     + NELEM)        // 524288
#define OFF_EMBT  (OFF_FHAT  + NELEM)        // 1048576 (tile-major codebook)
#define OFF_ESQ   (OFF_EMBT  + VV*CC)        // 1179648
#define OFF_PW    (OFF_ESQ   + VV)           // 1183744
#define OFF_PB    (OFF_PW    + 4*CC*CC*9)    // 1220608
#define OFF_REST  (OFF_PB    + 4*CC)         // 1220736 (row-major, max 16384*32)
#define OFF_BESTA (OFF_REST  + 16384*CC)     // 1745024 (16384 u64)
#define OFF_BESTB (OFF_BESTA + 2*16384)      // 1777792
#define OFF_LOSS  (OFF_BESTB + 2*16384)      // 1810560
#define OFF_FLAG  (OFF_LOSS  + 1)
#define OFF_EMBR  (OFF_FLAG  + 1)            // 1810562: optional row-major codebook
#define WS_NEED_EMBR ((OFF_EMBR + VV*CC) * 4)  // ~7.77 MB

// embT layout: embT[v>>6][c][v&63]  (tile stride 2048 floats, row stride 64)
__device__ __forceinline__ int embt_idx(int v, int c) {
    return (v >> 6) * 2048 + c * 64 + (v & 63);
}

// ---------------- dtype probe: is input 0 f32 (1) or bf16 (0)? ----------------
__global__ void k_probe(const void* __restrict__ fin, int* __restrict__ flag) {
    __shared__ int cnt[256];
    int t = threadIdx.x;
    const __hip_bfloat16* p = (const __hip_bfloat16*)fin;
    int local = 0;
    for (int i = t; i < 8192; i += 256) {
        float v = __bfloat162float(p[i]);
        if (!(fabsf(v) < 1e3f)) local++;
    }
    cnt[t] = local;
    __syncthreads();
    for (int s = 128; s > 0; s >>= 1) {
        if (t < s) cnt[t] += cnt[t + s];
        __syncthreads();
    }
    if (t == 0) *flag = (cnt[0] >= 64) ? 1 : 0;
}

// ---------------- prep: decode -> f32 ws (codebook into tile-major embT,
//                  plus optional row-major embR for fast gathers) -------------
__global__ void k_prep(const void* __restrict__ fin,
                       const void* __restrict__ ein,
                       const void* __restrict__ win,
                       const void* __restrict__ bin_,
                       const int* __restrict__ flag,
                       float* __restrict__ f, float* __restrict__ fhat,
                       float* __restrict__ embT, float* __restrict__ pw,
                       float* __restrict__ pb, float* __restrict__ loss,
                       float* __restrict__ embR, int use_embR) {
    bool isf32 = (*flag != 0);
    int i = blockIdx.x * 256 + threadIdx.x;
    if (i < NELEM) {
        f[i] = isf32 ? ((const float*)fin)[i]
                     : __bfloat162float(((const __hip_bfloat16*)fin)[i]);
        fhat[i] = 0.f;
    }
    if (i < VV*CC) {
        float ev = isf32 ? ((const float*)ein)[i]
                         : __bfloat162float(((const __hip_bfloat16*)ein)[i]);
        int v = i >> 5, c = i & 31;
        embT[embt_idx(v, c)] = ev;
        if (use_embR) embR[i] = ev;      // row-major [v][c]
    }
    if (i < 4*CC*CC*9)
        pw[i] = isf32 ? ((const float*)win)[i]
                      : __bfloat162float(((const __hip_bfloat16*)win)[i]);
    if (i < 4*CC)
        pb[i] = isf32 ? ((const float*)bin_)[i]
                      : __bfloat162float(((const __hip_bfloat16*)bin_)[i]);
    if (i == 0) *loss = 0.f;
}

__global__ void k_esq(const float* __restrict__ embT, float* __restrict__ esq) {
    int v = blockIdx.x * 256 + threadIdx.x;
    if (v >= VV) return;
    const float* p = embT + (v >> 6) * 2048 + (v & 63);
    float s = 0.f;
    #pragma unroll
    for (int c = 0; c < CC; ++c) { float e = p[c * 64]; s = fmaf(e, e, s); }
    esq[v] = s;
}

// ---------------- pool for scale 0 only (pn=1), row-major rest, init bestA ----
__global__ void k_pool0(const float* __restrict__ f, const float* __restrict__ fhat,
                        float* __restrict__ rest, unsigned long long* __restrict__ best) {
    int n = threadIdx.x;     // grid (1, 32)
    int c = blockIdx.y;
    if (n >= BB) return;
    if (c == 0) best[n] = 0xFFFFFFFFFFFFFFFFull;
    const float* fb = f + (n * CC + c) * HW2;
    const float* hb = fhat + (n * CC + c) * HW2;
    float s = 0.f;
    for (int h = 0; h < 16; ++h)
        for (int w = 0; w < 16; ++w)
            s += fb[h * 16 + w] - hb[h * 16 + w];
    rest[n * CC + c] = s * (1.f / 256.f);
}

// ---------------- argmin (big scales): r4's PROVEN 8q x 8c, 128q x 128-code
// tiles, K=32. 4 ds_read_b128 per 64 FMA-instrs; acc[8][8]=64 regs, no spill.
// Math bit-identical: fmaf chains k-ascending, xx = sum(c<16)+sum(c>=16),
// dist = fmaf(-2,acc,xx+es), strict-< index-ascending scan, packed-u64
// atomicMin (ties -> lowest idx).
__global__ __launch_bounds__(256, 3)
void k_argmin_big(const float* __restrict__ rest, const float* __restrict__ embT,
                  const float* __restrict__ esq, unsigned long long* __restrict__ best,
                  int Ntot, int cpw) {
    __shared__ float xT[CC][132];    // [c][q], 128 queries, rows 16B-aligned
    __shared__ float eT[2 * CC * 64];// two 64-code subtiles, embT tile layout
    __shared__ float xxs[2][128];
    int tid = threadIdx.x;
    int tx = tid & 15, ty = tid >> 4;
    int qblk = blockIdx.x * 128;
    int v0 = blockIdx.y * cpw;
    int t0 = v0 >> 6;

    // stage xT (transpose) + partial xx: thread = (query tid>>1, half tid&1)
    {
        int q = tid >> 1, h = tid & 1;
        int qq = qblk + q; if (qq > Ntot - 1) qq = Ntot - 1;
        const float* xr = rest + qq * CC + h * 16;
        float part = 0.f;
        #pragma unroll
        for (int c = 0; c < 16; ++c) {
            float xv = xr[c];
            xT[h * 16 + c][q] = xv;
            part = fmaf(xv, xv, part);
        }
        xxs[h][q] = part;
    }
    __syncthreads();

    float xx[8];
    #pragma unroll
    for (int i = 0; i < 8; ++i) {
        int q = (i >> 2) * 64 + ty * 4 + (i & 3);
        xx[i] = xxs[0][q] + xxs[1][q];
    }

    float bd[8]; int bi[8];
    #pragma unroll
    for (int i = 0; i < 8; ++i) { bd[i] = 3.4e38f; bi[i] = v0; }

    int ntiles = cpw >> 7;               // 128 codes per tile
    for (int t = 0; t < ntiles; ++t) {
        int vbase = v0 + t * 128;
        const float* gt = embT + (size_t)(t0 + 2 * t) * 2048;
        float4 s0 = *(const float4*)(gt + tid * 4);
        float4 s1 = *(const float4*)(gt + 1024 + tid * 4);
        float4 s2 = *(const float4*)(gt + 2048 + tid * 4);
        float4 s3 = *(const float4*)(gt + 3072 + tid * 4);
        __syncthreads();                 // prior tile's eT reads complete
        *(float4*)(eT + tid * 4) = s0;
        *(float4*)(eT + 1024 + tid * 4) = s1;
        *(float4*)(eT + 2048 + tid * 4) = s2;
        *(float4*)(eT + 3072 + tid * 4) = s3;
        __syncthreads();

        float acc[8][8];
        #pragma unroll
        for (int i = 0; i < 8; ++i)
            #pragma unroll
            for (int j = 0; j < 8; ++j) acc[i][j] = 0.f;

        #pragma unroll 8
        for (int k = 0; k < CC; ++k) {
            float4 a0 = *(const float4*)&xT[k][ty * 4];        // 4-distinct bcast
            float4 a1 = *(const float4*)&xT[k][64 + ty * 4];
            float4 b0 = *(const float4*)(eT + k * 64 + tx * 4);        // 2-way free
            float4 b1 = *(const float4*)(eT + 2048 + k * 64 + tx * 4); // 2-way free
            float a[8] = {a0.x, a0.y, a0.z, a0.w, a1.x, a1.y, a1.z, a1.w};
            float b[8] = {b0.x, b0.y, b0.z, b0.w, b1.x, b1.y, b1.z, b1.w};
            #pragma unroll
            for (int i = 0; i < 8; ++i)
                #pragma unroll
                for (int j = 0; j < 8; ++j)
                    acc[i][j] = fmaf(a[i], b[j], acc[i][j]);
        }

        float4 e0 = *(const float4*)(esq + vbase + tx * 4);       // L1-hot
        float4 e1 = *(const float4*)(esq + vbase + 64 + tx * 4);
        float es[8] = {e0.x, e0.y, e0.z, e0.w, e1.x, e1.y, e1.z, e1.w};
        #pragma unroll
        for (int i = 0; i < 8; ++i) {
            float base = xx[i];
            #pragma unroll
            for (int j = 0; j < 8; ++j) {
                float dist = fmaf(-2.f, acc[i][j], base + es[j]);
                int vidx = vbase + (j >> 2) * 64 + tx * 4 + (j & 3);
                if (dist < bd[i]) { bd[i] = dist; bi[i] = vidx; }
            }
        }
    }

    #pragma unroll
    for (int i = 0; i < 8; ++i) {
        unsigned u = __float_as_uint(bd[i]);
        unsigned long long mono = (u & 0x80000000u)
            ? (unsigned long long)(~u)
            : (unsigned long long)(u | 0x80000000u);
        unsigned long long pk = (mono << 32) | (unsigned long long)(unsigned)bi[i];
        #pragma unroll
        for (int m = 1; m <= 8; m <<= 1) {
            unsigned long long o = __shfl_xor(pk, m, 64);
            if (o < pk) pk = o;
        }
        int q = qblk + (i >> 2) * 64 + ty * 4 + (i & 3);
        if (tx == 0 && q < Ntot)
            atomicMin(best + q, pk);
    }
}

// ---------------- argmin (small scales, pn<=6): r1's proven no-barrier kernel.
__global__ __launch_bounds__(256, 4)
void k_argmin_small(const float* __restrict__ rest, const float* __restrict__ embT,
                    const float* __restrict__ esq, unsigned long long* __restrict__ best,
                    int Ntot, int cpw) {
    int tid  = threadIdx.x;
    int w    = tid >> 6, lane = tid & 63;
    int q0   = blockIdx.x * 512 + w * 128 + lane;
    int q1   = q0 + 64;
    int v0   = blockIdx.y * cpw;

    bool act0 = (q0 < Ntot), act1 = (q1 < Ntot);
    if (!act0 && !act1) return;
    int qa = act0 ? q0 : (Ntot - 1);
    int qb = act1 ? q1 : (Ntot - 1);

    float a0v[32], a1v[32];
    {
        const float4* ra = (const float4*)(rest + qa * CC);
        const float4* rb = (const float4*)(rest + qb * CC);
        #pragma unroll
        for (int c4 = 0; c4 < 8; ++c4) {
            float4 va = ra[c4], vb4 = rb[c4];
            a0v[c4*4+0] = va.x;  a0v[c4*4+1] = va.y;
            a0v[c4*4+2] = va.z;  a0v[c4*4+3] = va.w;
            a1v[c4*4+0] = vb4.x; a1v[c4*4+1] = vb4.y;
            a1v[c4*4+2] = vb4.z; a1v[c4*4+3] = vb4.w;
        }
    }

    float p0a = 0.f, p1a = 0.f, p0b = 0.f, p1b = 0.f;
    #pragma unroll
    for (int c = 0; c < 16; ++c)  p0a = fmaf(a0v[c], a0v[c], p0a);
    #pragma unroll
    for (int c = 16; c < 32; ++c) p1a = fmaf(a0v[c], a0v[c], p1a);
    #pragma unroll
    for (int c = 0; c < 16; ++c)  p0b = fmaf(a1v[c], a1v[c], p0b);
    #pragma unroll
    for (int c = 16; c < 32; ++c) p1b = fmaf(a1v[c], a1v[c], p1b);
    float xx0 = p0a + p1a;
    float xx1 = p0b + p1b;

    float bd0 = 3.4e38f, bd1 = 3.4e38f;
    int   bi0 = v0,      bi1 = v0;

    int ntiles = cpw >> 3;
    for (int t = 0; t < ntiles; ++t) {
        int vb = v0 + t * 8;
        int boff = __builtin_amdgcn_readfirstlane((vb >> 6) * 2048 + (vb & 63));
        int eoff = __builtin_amdgcn_readfirstlane(vb);
        const float* bt = embT + boff;
        const float* ep = esq + eoff;

        float acc0[8], acc1[8];
        #pragma unroll
        for (int j = 0; j < 8; ++j) { acc0[j] = 0.f; acc1[j] = 0.f; }

        #pragma unroll
        for (int k = 0; k < CC; ++k) {
            float a0 = a0v[k], a1 = a1v[k];
            #pragma unroll
            for (int j = 0; j < 8; ++j) {
                float bv = bt[k * 64 + j];
                acc0[j] = fmaf(a0, bv, acc0[j]);
                acc1[j] = fmaf(a1, bv, acc1[j]);
            }
        }

        #pragma unroll
        for (int j = 0; j < 8; ++j) {
            float es = ep[j];
            float d0 = fmaf(-2.f, acc0[j], xx0 + es);
            if (d0 < bd0) { bd0 = d0; bi0 = vb + j; }
            float d1 = fmaf(-2.f, acc1[j], xx1 + es);
            if (d1 < bd1) { bd1 = d1; bi1 = vb + j; }
        }
    }

    unsigned u0 = __float_as_uint(bd0);
    unsigned long long mono0 = (u0 & 0x80000000u)
        ? (unsigned long long)(~u0)
        : (unsigned long long)(u0 | 0x80000000u);
    unsigned long long pk0 = (mono0 << 32) | (unsigned long long)(unsigned)bi0;
    unsigned u1 = __float_as_uint(bd1);
    unsigned long long mono1 = (u1 & 0x80000000u)
        ? (unsigned long long)(~u1)
        : (unsigned long long)(u1 | 0x80000000u);
    unsigned long long pk1 = (mono1 << 32) | (unsigned long long)(unsigned)bi1;

    if (act0) atomicMin(best + q0, pk0);
    if (act1) atomicMin(best + q1, pk1);
}

// ---------------- fused: gather + upsample + conv3x3(phi) + f_hat + loss
//                  + pool(next scale) + best-init(next scale)
// grid (64,4) x 256 threads: block = (batch, 8-out-channel group).
// vs r4's (64,8): gather/upsample/h_pad build replicated 4x not 8x, and the
// conv does 8 outputs per hv window (LDS demand per CU halves; VALU/LDS
// balanced). Gather uses row-major embR (8x float4) when workspace permits.
__global__ __launch_bounds__(256)
void k_fuse(const float* __restrict__ embT,
            const unsigned long long* __restrict__ best,
            const float* __restrict__ pw, const float* __restrict__ pb,
            const float* __restrict__ f, float* __restrict__ fhat,
            float* __restrict__ loss,
            float* __restrict__ rest,
            unsigned long long* __restrict__ best_next,
            const float* __restrict__ embR,
            int pn, int k, int pn_next) {
    __shared__ float h_pad[CC * PADA];  // [c][18*18], halo = zero padding
    __shared__ float extra[CC * 169];   // hs during upsample, then diff[8][256]
    __shared__ float red[4];
    int b = blockIdx.x, co8 = blockIdx.y, t = threadIdx.x;
    int nn = pn * pn;
    int y = t >> 4, x = t & 15;

    for (int i = t; i < CC * PADA; i += 256) h_pad[i] = 0.f;

    if (pn == 16) {
        __syncthreads();
        int id = (int)(unsigned)(best[b * HW2 + t] & 0xFFFFFFFFull);
        int ctr = (y + 1) * PADW + (x + 1);
        if (embR) {
            const float4* er4 = (const float4*)(embR + id * CC);
            #pragma unroll
            for (int c4 = 0; c4 < 8; ++c4) {
                float4 v = er4[c4];
                h_pad[(c4*4+0) * PADA + ctr] = v.x;
                h_pad[(c4*4+1) * PADA + ctr] = v.y;
                h_pad[(c4*4+2) * PADA + ctr] = v.z;
                h_pad[(c4*4+3) * PADA + ctr] = v.w;
            }
        } else {
            const float* er = embT + (id >> 6) * 2048 + (id & 63);
            #pragma unroll
            for (int c = 0; c < CC; ++c)
                h_pad[c * PADA + ctr] = er[c * 64];
        }
    } else {
        float (*hs)[169] = (float(*)[169])extra;
        for (int cell = t; cell < nn; cell += 256) {
            int id = (int)(unsigned)(best[b * nn + cell] & 0xFFFFFFFFull);
            if (embR) {
                const float4* er4 = (const float4*)(embR + id * CC);
                #pragma unroll
                for (int c4 = 0; c4 < 8; ++c4) {
                    float4 v = er4[c4];
                    hs[c4*4+0][cell] = v.x;
                    hs[c4*4+1][cell] = v.y;
                    hs[c4*4+2][cell] = v.z;
                    hs[c4*4+3][cell] = v.w;
                }
            } else {
                const float* er = embT + (id >> 6) * 2048 + (id & 63);
                #pragma unroll
                for (int c = 0; c < CC; ++c) hs[c][cell] = er[c * 64];
            }
        }
        __syncthreads();
        float scale = (float)pn / 16.f;
        float sy = (y + 0.5f) * scale - 0.5f;
        sy = fminf(fmaxf(sy, 0.f), (float)(pn - 1));
        int y0 = (int)sy; int y1 = min(y0 + 1, pn - 1); float wy = sy - (float)y0;
        float sx = (x + 0.5f) * scale - 0.5f;
        sx = fminf(fmaxf(sx, 0.f), (float)(pn - 1));
        int x0 = (int)sx; int x1 = min(x0 + 1, pn - 1); float wx = sx - (float)x0;
        float wy0 = 1.f - wy, wx0 = 1.f - wx;
        int ctr = (y + 1) * PADW + (x + 1);
        #pragma unroll
        for (int c = 0; c < CC; ++c) {
            float v00 = hs[c][y0 * pn + x0], v01 = hs[c][y0 * pn + x1];
            float v10 = hs[c][y1 * pn + x0], v11 = hs[c][y1 * pn + x1];
            float a0 = wy0 * v00 + wy * v10;   // contract H first (jax resize order)
            float a1 = wy0 * v01 + wy * v11;
            h_pad[c * PADA + ctr] = wx0 * a0 + wx * a1;
        }
    }
    __syncthreads();

    float acc[8];
    #pragma unroll
    for (int o = 0; o < 8; ++o) acc[o] = 0.f;
    const float* hbase = h_pad + y * PADW + x;
    const float* wpk = pw + (k * CC + co8 * 8) * (CC * 9);   // block-uniform
    #pragma unroll
    for (int ci_ = 0; ci_ < CC; ++ci_) {
        float hv[9];
        #pragma unroll
        for (int dy = 0; dy < 3; ++dy)
            #pragma unroll
            for (int dx = 0; dx < 3; ++dx)
                hv[dy * 3 + dx] = hbase[ci_ * PADA + dy * PADW + dx];
        const float* wp = wpk + ci_ * 9;
        #pragma unroll
        for (int o = 0; o < 8; ++o) {
            const float* w9 = wp + o * (CC * 9);
            #pragma unroll
            for (int q = 0; q < 9; ++q) acc[o] = fmaf(hv[q], w9[q], acc[o]);
        }
    }

    float* diff = extra;   // [8][256], safe: extra unread after h_pad barrier
    float lsum = 0.f;
    int ctr = (y + 1) * PADW + (x + 1);
    #pragma unroll
    for (int o = 0; o < 8; ++o) {
        int co = co8 * 8 + o;
        float hval = h_pad[co * PADA + ctr];
        float outv = hval * 0.5f + (acc[o] + pb[k * CC + co]) * 0.5f;
        int pos = (b * CC + co) * HW2 + t;
        float fh = fhat[pos] + outv;
        fhat[pos] = fh;
        float dd = f[pos] - fh;
        diff[o * HW2 + t] = dd;
        lsum = fmaf(dd, dd, lsum);
    }
    #pragma unroll
    for (int off = 32; off > 0; off >>= 1) lsum += __shfl_down(lsum, off, 64);
    if ((t & 63) == 0) red[t >> 6] = lsum;
    __syncthreads();
    if (t == 0)
        atomicAdd(loss, red[0] + red[1] + red[2] + red[3]);

    if (pn_next > 0) {
        int nn2 = pn_next * pn_next;
        for (int q = t; q < nn2 * 8; q += 256) {
            int cell = q % nn2, o = q / nn2;
            int i = cell / pn_next, j = cell % pn_next;
            int s0 = (i * 16) / pn_next, e0 = ((i + 1) * 16 + pn_next - 1) / pn_next;
            int s1 = (j * 16) / pn_next, e1 = ((j + 1) * 16 + pn_next - 1) / pn_next;
            float inv = 1.f / (float)((e0 - s0) * (e1 - s1));
            float s = 0.f;
            for (int h = s0; h < e0; ++h)
                for (int w = s1; w < e1; ++w)
                    s += diff[o * HW2 + h * 16 + w];
            rest[(b * nn2 + cell) * CC + co8 * 8 + o] = s * inv;
        }
        if (co8 == 0)
            for (int q = t; q < nn2; q += 256)
                best_next[b * nn2 + q] = 0xFFFFFFFFFFFFFFFFull;
    }
}

// ---------------- writeout: f32 -> out dtype (matches probed input dtype) -----
__global__ void k_out(const float* __restrict__ fhat, const float* __restrict__ loss,
                      const int* __restrict__ flag, void* __restrict__ out) {
    bool isf32 = (*flag != 0);
    int i = blockIdx.x * 256 + threadIdx.x;
    if (i > NELEM) return;
    float v;
    if (i < NELEM) v = fhat[i];
    else           v = (*loss) * (1.25f / (float)NELEM / 8.f);
    if (isf32) ((float*)out)[i] = v;
    else       ((__hip_bfloat16*)out)[i] = __float2bfloat16(v);
}

extern "C" void kernel_launch(void* const* d_in, const int* in_sizes, int n_in,
                              void* d_out, int out_size, void* d_ws, size_t ws_size,
                              hipStream_t stream) {
    const void* fin  = d_in[0];
    const void* ein  = d_in[1];
    const void* win  = d_in[2];
    const void* bin_ = d_in[3];
    float* ws = (float*)d_ws;
    float* f    = ws + OFF_F;
    float* fhat = ws + OFF_FHAT;
    float* embT = ws + OFF_EMBT;
    float* esq  = ws + OFF_ESQ;
    float* pw   = ws + OFF_PW;
    float* pb   = ws + OFF_PB;
    float* rest = ws + OFF_REST;
    unsigned long long* bestA = (unsigned long long*)(ws + OFF_BESTA);
    unsigned long long* bestB = (unsigned long long*)(ws + OFF_BESTB);
    float* loss = ws + OFF_LOSS;
    int*   flag = (int*)(ws + OFF_FLAG);
    int use_embR = (ws_size >= (size_t)WS_NEED_EMBR) ? 1 : 0;
    float* embR = use_embR ? (ws + OFF_EMBR) : nullptr;

    static const int PN[8] = {1, 2, 4, 6, 8, 10, 13, 16};
    static const int KK[8] = {0, 0, 1, 1, 2, 2, 3, 3};
    // small scales (si<4): r1 kernel, 512 q/block, many code-splits
    static const int SPs[4] = {512, 512, 512, 256};
    // big scales (si>=4): r4's 128q x 128-code LDS GEMM; cpw multiple of 128
    static const int SPb[4] = {16, 16, 8, 8};

    k_probe<<<1, 256, 0, stream>>>(fin, flag);
    k_prep<<<(NELEM + 255) / 256, 256, 0, stream>>>(fin, ein, win, bin_, flag,
                                                    f, fhat, embT, pw, pb, loss,
                                                    embR, use_embR);
    k_esq<<<(VV + 255) / 256, 256, 0, stream>>>(embT, esq);
    k_pool0<<<dim3(1, CC), 256, 0, stream>>>(f, fhat, rest, bestA);

    for (int si = 0; si < 8; ++si) {
        int pn = PN[si];
        int Ntot = BB * pn * pn;
        unsigned long long* bcur = (si & 1) ? bestB : bestA;
        unsigned long long* bnxt = (si & 1) ? bestA : bestB;
        int pn_next = (si < 7) ? PN[si + 1] : 0;
        if (si < 4) {
            int Sp = SPs[si];
            int cpw = VV / Sp;
            int gx = (Ntot + 511) / 512;
            k_argmin_small<<<dim3(gx, Sp), 256, 0, stream>>>(rest, embT, esq, bcur,
                                                             Ntot, cpw);
        } else {
            int Sp = SPb[si - 4];
            int cpw = VV / Sp;
            int gx = (Ntot + 127) / 128;
            k_argmin_big<<<dim3(gx, Sp), 256, 0, stream>>>(rest, embT, esq, bcur,
                                                           Ntot, cpw);
        }
        k_fuse<<<dim3(BB, 4), 256, 0, stream>>>(embT, bcur, pw, pb, f, fhat, loss,
                                                rest, bnxt, embR, pn, KK[si], pn_next);
    }
    k_out<<<(NELEM + 1 + 255) / 256, 256, 0, stream>>>(fhat, loss, flag, d_out);
}

// Round 7
// 446.973 us; speedup vs baseline: 1.0894x; 1.0894x over previous
//
#include <hip/hip_runtime.h>
#include <hip/hip_bf16.h>

#define BB 64
#define CC 32
#define HW2 256   // 16*16
#define VV 4096
#define NELEM (BB*CC*HW2)   // 524288
#define PADW 18
#define PADA 324  // 18*18

// ---------------- workspace layout (float offsets) ----------------
#define OFF_F     0
#define OFF_FHAT  (OFF_F     + NELEM)        // 524288
#define OFF_EMBT  (OFF_FHAT  + NELEM)        // 1048576 (tile-major codebook)
#define OFF_ESQ   (OFF_EMBT  + VV*CC)        // 1179648
#define OFF_PW    (OFF_ESQ   + VV)           // 1183744
#define OFF_PB    (OFF_PW    + 4*CC*CC*9)    // 1220608
#define OFF_REST  (OFF_PB    + 4*CC)         // 1220736 (row-major, max 16384*32)
#define OFF_BESTA (OFF_REST  + 16384*CC)     // 1745024 (16384 u64)
#define OFF_BESTB (OFF_BESTA + 2*16384)      // 1777792
#define OFF_LOSS  (OFF_BESTB + 2*16384)      // 1810560
#define OFF_FLAG  (OFF_LOSS  + 1)
#define OFF_EMBR  (OFF_FLAG  + 1)            // 1810562: optional row-major codebook
#define WS_NEED_EMBR ((OFF_EMBR + VV*CC) * 4)  // ~7.77 MB

// embT layout: embT[v>>6][c][v&63]  (tile stride 2048 floats, row stride 64)
__device__ __forceinline__ int embt_idx(int v, int c) {
    return (v >> 6) * 2048 + c * 64 + (v & 63);
}

// ---------------- dtype probe: is input 0 f32 (1) or bf16 (0)? ----------------
__global__ void k_probe(const void* __restrict__ fin, int* __restrict__ flag) {
    __shared__ int cnt[256];
    int t = threadIdx.x;
    const __hip_bfloat16* p = (const __hip_bfloat16*)fin;
    int local = 0;
    for (int i = t; i < 8192; i += 256) {
        float v = __bfloat162float(p[i]);
        if (!(fabsf(v) < 1e3f)) local++;
    }
    cnt[t] = local;
    __syncthreads();
    for (int s = 128; s > 0; s >>= 1) {
        if (t < s) cnt[t] += cnt[t + s];
        __syncthreads();
    }
    if (t == 0) *flag = (cnt[0] >= 64) ? 1 : 0;
}

// ---------------- prep: decode -> f32 ws (codebook into tile-major embT,
//                  plus optional row-major embR for fast gathers) -------------
__global__ void k_prep(const void* __restrict__ fin,
                       const void* __restrict__ ein,
                       const void* __restrict__ win,
                       const void* __restrict__ bin_,
                       const int* __restrict__ flag,
                       float* __restrict__ f, float* __restrict__ fhat,
                       float* __restrict__ embT, float* __restrict__ pw,
                       float* __restrict__ pb, float* __restrict__ loss,
                       float* __restrict__ embR, int use_embR) {
    bool isf32 = (*flag != 0);
    int i = blockIdx.x * 256 + threadIdx.x;
    if (i < NELEM) {
        f[i] = isf32 ? ((const float*)fin)[i]
                     : __bfloat162float(((const __hip_bfloat16*)fin)[i]);
        fhat[i] = 0.f;
    }
    if (i < VV*CC) {
        float ev = isf32 ? ((const float*)ein)[i]
                         : __bfloat162float(((const __hip_bfloat16*)ein)[i]);
        int v = i >> 5, c = i & 31;
        embT[embt_idx(v, c)] = ev;
        if (use_embR) embR[i] = ev;      // row-major [v][c]
    }
    if (i < 4*CC*CC*9)
        pw[i] = isf32 ? ((const float*)win)[i]
                      : __bfloat162float(((const __hip_bfloat16*)win)[i]);
    if (i < 4*CC)
        pb[i] = isf32 ? ((const float*)bin_)[i]
                      : __bfloat162float(((const __hip_bfloat16*)bin_)[i]);
    if (i == 0) *loss = 0.f;
}

__global__ void k_esq(const float* __restrict__ embT, float* __restrict__ esq) {
    int v = blockIdx.x * 256 + threadIdx.x;
    if (v >= VV) return;
    const float* p = embT + (v >> 6) * 2048 + (v & 63);
    float s = 0.f;
    #pragma unroll
    for (int c = 0; c < CC; ++c) { float e = p[c * 64]; s = fmaf(e, e, s); }
    esq[v] = s;
}

// ---------------- pool for scale 0 only (pn=1), row-major rest, init bestA ----
__global__ void k_pool0(const float* __restrict__ f, const float* __restrict__ fhat,
                        float* __restrict__ rest, unsigned long long* __restrict__ best) {
    int n = threadIdx.x;     // grid (1, 32)
    int c = blockIdx.y;
    if (n >= BB) return;
    if (c == 0) best[n] = 0xFFFFFFFFFFFFFFFFull;
    const float* fb = f + (n * CC + c) * HW2;
    const float* hb = fhat + (n * CC + c) * HW2;
    float s = 0.f;
    for (int h = 0; h < 16; ++h)
        for (int w = 0; w < 16; ++w)
            s += fb[h * 16 + w] - hb[h * 16 + w];
    rest[n * CC + c] = s * (1.f / 256.f);
}

// ---------------- argmin (big scales): r4's PROVEN 8q x 8c, 128q x 128-code
// tiles, K=32. 4 ds_read_b128 per 64 FMA-instrs; acc[8][8]=64 regs, no spill.
// Math bit-identical: fmaf chains k-ascending, xx = sum(c<16)+sum(c>=16),
// dist = fmaf(-2,acc,xx+es), strict-< index-ascending scan, packed-u64
// atomicMin (ties -> lowest idx).
__global__ __launch_bounds__(256, 3)
void k_argmin_big(const float* __restrict__ rest, const float* __restrict__ embT,
                  const float* __restrict__ esq, unsigned long long* __restrict__ best,
                  int Ntot, int cpw) {
    __shared__ float xT[CC][132];    // [c][q], 128 queries, rows 16B-aligned
    __shared__ float eT[2 * CC * 64];// two 64-code subtiles, embT tile layout
    __shared__ float xxs[2][128];
    int tid = threadIdx.x;
    int tx = tid & 15, ty = tid >> 4;
    int qblk = blockIdx.x * 128;
    int v0 = blockIdx.y * cpw;
    int t0 = v0 >> 6;

    // stage xT (transpose) + partial xx: thread = (query tid>>1, half tid&1)
    {
        int q = tid >> 1, h = tid & 1;
        int qq = qblk + q; if (qq > Ntot - 1) qq = Ntot - 1;
        const float* xr = rest + qq * CC + h * 16;
        float part = 0.f;
        #pragma unroll
        for (int c = 0; c < 16; ++c) {
            float xv = xr[c];
            xT[h * 16 + c][q] = xv;
            part = fmaf(xv, xv, part);
        }
        xxs[h][q] = part;
    }
    __syncthreads();

    float xx[8];
    #pragma unroll
    for (int i = 0; i < 8; ++i) {
        int q = (i >> 2) * 64 + ty * 4 + (i & 3);
        xx[i] = xxs[0][q] + xxs[1][q];
    }

    float bd[8]; int bi[8];
    #pragma unroll
    for (int i = 0; i < 8; ++i) { bd[i] = 3.4e38f; bi[i] = v0; }

    int ntiles = cpw >> 7;               // 128 codes per tile
    for (int t = 0; t < ntiles; ++t) {
        int vbase = v0 + t * 128;
        const float* gt = embT + (size_t)(t0 + 2 * t) * 2048;
        float4 s0 = *(const float4*)(gt + tid * 4);
        float4 s1 = *(const float4*)(gt + 1024 + tid * 4);
        float4 s2 = *(const float4*)(gt + 2048 + tid * 4);
        float4 s3 = *(const float4*)(gt + 3072 + tid * 4);
        __syncthreads();                 // prior tile's eT reads complete
        *(float4*)(eT + tid * 4) = s0;
        *(float4*)(eT + 1024 + tid * 4) = s1;
        *(float4*)(eT + 2048 + tid * 4) = s2;
        *(float4*)(eT + 3072 + tid * 4) = s3;
        __syncthreads();

        float acc[8][8];
        #pragma unroll
        for (int i = 0; i < 8; ++i)
            #pragma unroll
            for (int j = 0; j < 8; ++j) acc[i][j] = 0.f;

        #pragma unroll 8
        for (int k = 0; k < CC; ++k) {
            float4 a0 = *(const float4*)&xT[k][ty * 4];        // 4-distinct bcast
            float4 a1 = *(const float4*)&xT[k][64 + ty * 4];
            float4 b0 = *(const float4*)(eT + k * 64 + tx * 4);        // 2-way free
            float4 b1 = *(const float4*)(eT + 2048 + k * 64 + tx * 4); // 2-way free
            float a[8] = {a0.x, a0.y, a0.z, a0.w, a1.x, a1.y, a1.z, a1.w};
            float b[8] = {b0.x, b0.y, b0.z, b0.w, b1.x, b1.y, b1.z, b1.w};
            #pragma unroll
            for (int i = 0; i < 8; ++i)
                #pragma unroll
                for (int j = 0; j < 8; ++j)
                    acc[i][j] = fmaf(a[i], b[j], acc[i][j]);
        }

        float4 e0 = *(const float4*)(esq + vbase + tx * 4);       // L1-hot
        float4 e1 = *(const float4*)(esq + vbase + 64 + tx * 4);
        float es[8] = {e0.x, e0.y, e0.z, e0.w, e1.x, e1.y, e1.z, e1.w};
        #pragma unroll
        for (int i = 0; i < 8; ++i) {
            float base = xx[i];
            #pragma unroll
            for (int j = 0; j < 8; ++j) {
                float dist = fmaf(-2.f, acc[i][j], base + es[j]);
                int vidx = vbase + (j >> 2) * 64 + tx * 4 + (j & 3);
                if (dist < bd[i]) { bd[i] = dist; bi[i] = vidx; }
            }
        }
    }

    #pragma unroll
    for (int i = 0; i < 8; ++i) {
        unsigned u = __float_as_uint(bd[i]);
        unsigned long long mono = (u & 0x80000000u)
            ? (unsigned long long)(~u)
            : (unsigned long long)(u | 0x80000000u);
        unsigned long long pk = (mono << 32) | (unsigned long long)(unsigned)bi[i];
        #pragma unroll
        for (int m = 1; m <= 8; m <<= 1) {
            unsigned long long o = __shfl_xor(pk, m, 64);
            if (o < pk) pk = o;
        }
        int q = qblk + (i >> 2) * 64 + ty * 4 + (i & 3);
        if (tx == 0 && q < Ntot)
            atomicMin(best + q, pk);
    }
}

// ---------------- argmin (small scales, pn<=6): r1's proven no-barrier kernel.
__global__ __launch_bounds__(256, 4)
void k_argmin_small(const float* __restrict__ rest, const float* __restrict__ embT,
                    const float* __restrict__ esq, unsigned long long* __restrict__ best,
                    int Ntot, int cpw) {
    int tid  = threadIdx.x;
    int w    = tid >> 6, lane = tid & 63;
    int q0   = blockIdx.x * 512 + w * 128 + lane;
    int q1   = q0 + 64;
    int v0   = blockIdx.y * cpw;

    bool act0 = (q0 < Ntot), act1 = (q1 < Ntot);
    if (!act0 && !act1) return;
    int qa = act0 ? q0 : (Ntot - 1);
    int qb = act1 ? q1 : (Ntot - 1);

    float a0v[32], a1v[32];
    {
        const float4* ra = (const float4*)(rest + qa * CC);
        const float4* rb = (const float4*)(rest + qb * CC);
        #pragma unroll
        for (int c4 = 0; c4 < 8; ++c4) {
            float4 va = ra[c4], vb4 = rb[c4];
            a0v[c4*4+0] = va.x;  a0v[c4*4+1] = va.y;
            a0v[c4*4+2] = va.z;  a0v[c4*4+3] = va.w;
            a1v[c4*4+0] = vb4.x; a1v[c4*4+1] = vb4.y;
            a1v[c4*4+2] = vb4.z; a1v[c4*4+3] = vb4.w;
        }
    }

    float p0a = 0.f, p1a = 0.f, p0b = 0.f, p1b = 0.f;
    #pragma unroll
    for (int c = 0; c < 16; ++c)  p0a = fmaf(a0v[c], a0v[c], p0a);
    #pragma unroll
    for (int c = 16; c < 32; ++c) p1a = fmaf(a0v[c], a0v[c], p1a);
    #pragma unroll
    for (int c = 0; c < 16; ++c)  p0b = fmaf(a1v[c], a1v[c], p0b);
    #pragma unroll
    for (int c = 16; c < 32; ++c) p1b = fmaf(a1v[c], a1v[c], p1b);
    float xx0 = p0a + p1a;
    float xx1 = p0b + p1b;

    float bd0 = 3.4e38f, bd1 = 3.4e38f;
    int   bi0 = v0,      bi1 = v0;

    int ntiles = cpw >> 3;
    for (int t = 0; t < ntiles; ++t) {
        int vb = v0 + t * 8;
        int boff = __builtin_amdgcn_readfirstlane((vb >> 6) * 2048 + (vb & 63));
        int eoff = __builtin_amdgcn_readfirstlane(vb);
        const float* bt = embT + boff;
        const float* ep = esq + eoff;

        float acc0[8], acc1[8];
        #pragma unroll
        for (int j = 0; j < 8; ++j) { acc0[j] = 0.f; acc1[j] = 0.f; }

        #pragma unroll
        for (int k = 0; k < CC; ++k) {
            float a0 = a0v[k], a1 = a1v[k];
            #pragma unroll
            for (int j = 0; j < 8; ++j) {
                float bv = bt[k * 64 + j];
                acc0[j] = fmaf(a0, bv, acc0[j]);
                acc1[j] = fmaf(a1, bv, acc1[j]);
            }
        }

        #pragma unroll
        for (int j = 0; j < 8; ++j) {
            float es = ep[j];
            float d0 = fmaf(-2.f, acc0[j], xx0 + es);
            if (d0 < bd0) { bd0 = d0; bi0 = vb + j; }
            float d1 = fmaf(-2.f, acc1[j], xx1 + es);
            if (d1 < bd1) { bd1 = d1; bi1 = vb + j; }
        }
    }

    unsigned u0 = __float_as_uint(bd0);
    unsigned long long mono0 = (u0 & 0x80000000u)
        ? (unsigned long long)(~u0)
        : (unsigned long long)(u0 | 0x80000000u);
    unsigned long long pk0 = (mono0 << 32) | (unsigned long long)(unsigned)bi0;
    unsigned u1 = __float_as_uint(bd1);
    unsigned long long mono1 = (u1 & 0x80000000u)
        ? (unsigned long long)(~u1)
        : (unsigned long long)(u1 | 0x80000000u);
    unsigned long long pk1 = (mono1 << 32) | (unsigned long long)(unsigned)bi1;

    if (act0) atomicMin(best + q0, pk0);
    if (act1) atomicMin(best + q1, pk1);
}

// ---------------- fused: gather + upsample + conv3x3(phi) + f_hat + loss
//                  + pool(next scale) + best-init(next scale)
// grid (64,8) x 256 threads (2 blocks/CU, 8 waves/CU — r4's proven occupancy).
// r7 changes vs r4: (1) halo-only LDS zeroing (68 cells/ch vs 324; removes the
// pn==16 pre-barrier — halo and interior writes disjoint); (2) embR float4
// gather (8 dwordx4 vs 32 scattered scalars); (3) conv remapped to P=2 px x
// O=2 co per thread with WAVE-uniform co (weights stay on the s_load path):
// window = 6 ds_read_b64/ci (8B-aligned: 324,18,x0 all even) feeding 36 FMAs
// vs 9 scalar reads per 36 FMAs. Per-output fmaf chain unchanged (ci asc,
// q asc) -> f_hat bit-identical to r4; only the loss-sum grouping changes
// (output scalar only, no feedback into argmin).
__global__ __launch_bounds__(256)
void k_fuse(const float* __restrict__ embT,
            const unsigned long long* __restrict__ best,
            const float* __restrict__ pw, const float* __restrict__ pb,
            const float* __restrict__ f, float* __restrict__ fhat,
            float* __restrict__ loss,
            float* __restrict__ rest,
            unsigned long long* __restrict__ best_next,
            const float* __restrict__ embR,
            int pn, int k, int pn_next) {
    __shared__ float h_pad[CC * PADA];  // [c][18*18], halo = zero padding
    __shared__ float extra[CC * 169];   // hs during upsample, then diff[4][256]
    __shared__ float red[4];
    int b = blockIdx.x, co8 = blockIdx.y, t = threadIdx.x;
    int nn = pn * pn;
    int y = t >> 4, x = t & 15;

    // zero halo only: 68 perimeter cells per channel (rows 0,17 full 18;
    // cols 0,17 rows 1..16). Interior is fully written by gather/upsample.
    for (int i = t; i < CC * 68; i += 256) {
        int c = i / 68, cell = i % 68;
        int yy, xx;
        if (cell < 18)      { yy = 0;  xx = cell; }
        else if (cell < 36) { yy = 17; xx = cell - 18; }
        else if (cell < 52) { yy = cell - 36 + 1; xx = 0; }
        else                { yy = cell - 52 + 1; xx = 17; }
        h_pad[c * PADA + yy * PADW + xx] = 0.f;
    }

    if (pn == 16) {
        // no barrier needed: halo (above) and interior (below) are disjoint
        int id = (int)(unsigned)(best[b * HW2 + t] & 0xFFFFFFFFull);
        int ctr = (y + 1) * PADW + (x + 1);
        if (embR) {
            const float4* er4 = (const float4*)(embR + id * CC);
            #pragma unroll
            for (int c4 = 0; c4 < 8; ++c4) {
                float4 v = er4[c4];
                h_pad[(c4*4+0) * PADA + ctr] = v.x;
                h_pad[(c4*4+1) * PADA + ctr] = v.y;
                h_pad[(c4*4+2) * PADA + ctr] = v.z;
                h_pad[(c4*4+3) * PADA + ctr] = v.w;
            }
        } else {
            const float* er = embT + (id >> 6) * 2048 + (id & 63);
            #pragma unroll
            for (int c = 0; c < CC; ++c)
                h_pad[c * PADA + ctr] = er[c * 64];
        }
    } else {
        float (*hs)[169] = (float(*)[169])extra;
        for (int cell = t; cell < nn; cell += 256) {
            int id = (int)(unsigned)(best[b * nn + cell] & 0xFFFFFFFFull);
            if (embR) {
                const float4* er4 = (const float4*)(embR + id * CC);
                #pragma unroll
                for (int c4 = 0; c4 < 8; ++c4) {
                    float4 v = er4[c4];
                    hs[c4*4+0][cell] = v.x;
                    hs[c4*4+1][cell] = v.y;
                    hs[c4*4+2][cell] = v.z;
                    hs[c4*4+3][cell] = v.w;
                }
            } else {
                const float* er = embT + (id >> 6) * 2048 + (id & 63);
                #pragma unroll
                for (int c = 0; c < CC; ++c) hs[c][cell] = er[c * 64];
            }
        }
        __syncthreads();   // hs visible (halo writes disjoint, also covered)
        float scale = (float)pn / 16.f;
        float sy = (y + 0.5f) * scale - 0.5f;
        sy = fminf(fmaxf(sy, 0.f), (float)(pn - 1));
        int y0 = (int)sy; int y1 = min(y0 + 1, pn - 1); float wy = sy - (float)y0;
        float sx = (x + 0.5f) * scale - 0.5f;
        sx = fminf(fmaxf(sx, 0.f), (float)(pn - 1));
        int x0 = (int)sx; int x1 = min(x0 + 1, pn - 1); float wx = sx - (float)x0;
        float wy0 = 1.f - wy, wx0 = 1.f - wx;
        int ctr = (y + 1) * PADW + (x + 1);
        #pragma unroll
        for (int c = 0; c < CC; ++c) {
            float v00 = hs[c][y0 * pn + x0], v01 = hs[c][y0 * pn + x1];
            float v10 = hs[c][y1 * pn + x0], v11 = hs[c][y1 * pn + x1];
            float a0 = wy0 * v00 + wy * v10;   // contract H first (jax resize order)
            float a1 = wy0 * v01 + wy * v11;
            h_pad[c * PADA + ctr] = wx0 * a0 + wx * a1;
        }
    }
    __syncthreads();   // h_pad ready; all reads of hs/extra done

    // ---- conv: wave-mapped P=2 pixels x O=2 channels ----
    int wv  = t >> 6, lane = t & 63;
    int cg  = wv & 1;                      // co-pair within block's 4
    int pg  = (wv >> 1) * 64 + lane;       // pixel-pair group 0..127
    int cy  = pg >> 3, cx0 = (pg & 7) * 2; // pixel row, first of 2 x
    int cob = co8 * 4 + cg * 2;            // first of 2 co (wave-uniform)
    int wuni = __builtin_amdgcn_readfirstlane(k * CC + cob);
    const float* wpk = pw + wuni * (CC * 9);

    float acc00 = 0.f, acc01 = 0.f, acc10 = 0.f, acc11 = 0.f; // [px][co]
    const float* hb0 = h_pad + cy * PADW + cx0;   // window top-left (padded)
    #pragma unroll
    for (int ci_ = 0; ci_ < CC; ++ci_) {
        float win[3][4];
        #pragma unroll
        for (int dy = 0; dy < 3; ++dy) {
            float2 r0 = *(const float2*)(hb0 + ci_ * PADA + dy * PADW);
            float2 r1 = *(const float2*)(hb0 + ci_ * PADA + dy * PADW + 2);
            win[dy][0] = r0.x; win[dy][1] = r0.y;
            win[dy][2] = r1.x; win[dy][3] = r1.y;
        }
        const float* w0 = wpk + ci_ * 9;
        const float* w1 = wpk + CC * 9 + ci_ * 9;
        #pragma unroll
        for (int q = 0; q < 9; ++q) {
            int dy = q / 3, dx = q % 3;
            float wv0 = w0[q], wv1 = w1[q];
            acc00 = fmaf(win[dy][dx],     wv0, acc00);
            acc01 = fmaf(win[dy][dx],     wv1, acc01);
            acc10 = fmaf(win[dy][dx + 1], wv0, acc10);
            acc11 = fmaf(win[dy][dx + 1], wv1, acc11);
        }
    }

    float* diff = extra;   // [4][256], safe: extra unread after h_pad barrier
    float lsum = 0.f;
    {
        int ctrc = (cy + 1) * PADW + (cx0 + 1);
        #pragma unroll
        for (int oo = 0; oo < 2; ++oo) {
            int co = cob + oo;
            float bias = pb[k * CC + co];
            float a0 = oo ? acc01 : acc00;   // px0
            float a1 = oo ? acc11 : acc10;   // px1
            int pos = (b * CC + co) * HW2 + cy * 16 + cx0;
            float2 fh2 = *(float2*)(fhat + pos);
            float2 f2  = *(const float2*)(f + pos);
            float hv0 = h_pad[co * PADA + ctrc];
            float hv1 = h_pad[co * PADA + ctrc + 1];
            float out0 = hv0 * 0.5f + (a0 + bias) * 0.5f;
            float out1 = hv1 * 0.5f + (a1 + bias) * 0.5f;
            fh2.x += out0; fh2.y += out1;
            *(float2*)(fhat + pos) = fh2;
            float dd0 = f2.x - fh2.x;
            float dd1 = f2.y - fh2.y;
            int dbase = (cg * 2 + oo) * HW2 + cy * 16 + cx0;
            diff[dbase]     = dd0;
            diff[dbase + 1] = dd1;
            lsum = fmaf(dd0, dd0, lsum);
            lsum = fmaf(dd1, dd1, lsum);
        }
    }
    #pragma unroll
    for (int off = 32; off > 0; off >>= 1) lsum += __shfl_down(lsum, off, 64);
    if ((t & 63) == 0) red[t >> 6] = lsum;
    __syncthreads();   // red + diff visible
    if (t == 0)
        atomicAdd(loss, red[0] + red[1] + red[2] + red[3]);

    if (pn_next > 0) {
        int nn2 = pn_next * pn_next;
        for (int q = t; q < nn2 * 4; q += 256) {
            int cell = q % nn2, o = q / nn2;
            int i = cell / pn_next, j = cell % pn_next;
            int s0 = (i * 16) / pn_next, e0 = ((i + 1) * 16 + pn_next - 1) / pn_next;
            int s1 = (j * 16) / pn_next, e1 = ((j + 1) * 16 + pn_next - 1) / pn_next;
            float inv = 1.f / (float)((e0 - s0) * (e1 - s1));
            float s = 0.f;
            for (int h = s0; h < e0; ++h)
                for (int w = s1; w < e1; ++w)
                    s += diff[o * HW2 + h * 16 + w];
            rest[(b * nn2 + cell) * CC + co8 * 4 + o] = s * inv;
        }
        if (co8 == 0)
            for (int q = t; q < nn2; q += 256)
                best_next[b * nn2 + q] = 0xFFFFFFFFFFFFFFFFull;
    }
}

// ---------------- writeout: f32 -> out dtype (matches probed input dtype) -----
__global__ void k_out(const float* __restrict__ fhat, const float* __restrict__ loss,
                      const int* __restrict__ flag, void* __restrict__ out) {
    bool isf32 = (*flag != 0);
    int i = blockIdx.x * 256 + threadIdx.x;
    if (i > NELEM) return;
    float v;
    if (i < NELEM) v = fhat[i];
    else           v = (*loss) * (1.25f / (float)NELEM / 8.f);
    if (isf32) ((float*)out)[i] = v;
    else       ((__hip_bfloat16*)out)[i] = __float2bfloat16(v);
}

extern "C" void kernel_launch(void* const* d_in, const int* in_sizes, int n_in,
                              void* d_out, int out_size, void* d_ws, size_t ws_size,
                              hipStream_t stream) {
    const void* fin  = d_in[0];
    const void* ein  = d_in[1];
    const void* win  = d_in[2];
    const void* bin_ = d_in[3];
    float* ws = (float*)d_ws;
    float* f    = ws + OFF_F;
    float* fhat = ws + OFF_FHAT;
    float* embT = ws + OFF_EMBT;
    float* esq  = ws + OFF_ESQ;
    float* pw   = ws + OFF_PW;
    float* pb   = ws + OFF_PB;
    float* rest = ws + OFF_REST;
    unsigned long long* bestA = (unsigned long long*)(ws + OFF_BESTA);
    unsigned long long* bestB = (unsigned long long*)(ws + OFF_BESTB);
    float* loss = ws + OFF_LOSS;
    int*   flag = (int*)(ws + OFF_FLAG);
    int use_embR = (ws_size >= (size_t)WS_NEED_EMBR) ? 1 : 0;
    float* embR = use_embR ? (ws + OFF_EMBR) : nullptr;

    static const int PN[8] = {1, 2, 4, 6, 8, 10, 13, 16};
    static const int KK[8] = {0, 0, 1, 1, 2, 2, 3, 3};
    // small scales (si<4): r1 kernel, 512 q/block, many code-splits
    static const int SPs[4] = {512, 512, 512, 256};
    // big scales (si>=4): r4's 128q x 128-code LDS GEMM; cpw multiple of 128
    static const int SPb[4] = {16, 16, 8, 8};

    k_probe<<<1, 256, 0, stream>>>(fin, flag);
    k_prep<<<(NELEM + 255) / 256, 256, 0, stream>>>(fin, ein, win, bin_, flag,
                                                    f, fhat, embT, pw, pb, loss,
                                                    embR, use_embR);
    k_esq<<<(VV + 255) / 256, 256, 0, stream>>>(embT, esq);
    k_pool0<<<dim3(1, CC), 256, 0, stream>>>(f, fhat, rest, bestA);

    for (int si = 0; si < 8; ++si) {
        int pn = PN[si];
        int Ntot = BB * pn * pn;
        unsigned long long* bcur = (si & 1) ? bestB : bestA;
        unsigned long long* bnxt = (si & 1) ? bestA : bestB;
        int pn_next = (si < 7) ? PN[si + 1] : 0;
        if (si < 4) {
            int Sp = SPs[si];
            int cpw = VV / Sp;
            int gx = (Ntot + 511) / 512;
            k_argmin_small<<<dim3(gx, Sp), 256, 0, stream>>>(rest, embT, esq, bcur,
                                                             Ntot, cpw);
        } else {
            int Sp = SPb[si - 4];
            int cpw = VV / Sp;
            int gx = (Ntot + 127) / 128;
            k_argmin_big<<<dim3(gx, Sp), 256, 0, stream>>>(rest, embT, esq, bcur,
                                                           Ntot, cpw);
        }
        k_fuse<<<dim3(BB, 8), 256, 0, stream>>>(embT, bcur, pw, pb, f, fhat, loss,
                                                rest, bnxt, embR, pn, KK[si], pn_next);
    }
    k_out<<<(NELEM + 1 + 255) / 256, 256, 0, stream>>>(fhat, loss, flag, d_out);
}